// Round 10
// baseline (145793.530 us; speedup 1.0000x reference)
//
#include <hip/hip_runtime.h>
#include <hip/hip_bf16.h>
#include <math.h>
#include <stdio.h>

#define NWG 256
#define NT  512
#define T_  128
#define L_  8
typedef unsigned short ushort_t;

struct P {
  const float *data,*r,*y_d,*wte_w,*wte_b,*wpe,*ln1_w,*ln1_b,*qkv_w,*qkv_b,
              *proj_w,*proj_b,*ln2_w,*ln2_b,*fc_w,*fc_b,*mproj_w,*mproj_b,
              *lnf_w,*lnf_b,*head_w,*head_b;
  float *out, *y, *u, *h0, *h1, *pP, *pM;
  ushort_t *qT, *oT, *gT;                 // bf16 activations
  ushort_t *wq, *wp, *wf, *wm;            // bf16 weights (converted at launch)
  ushort_t *Kc, *Vc;
  unsigned long long *sync;
};

__device__ __forceinline__ float bf2f(ushort_t u) {
  return __uint_as_float(((unsigned)u) << 16);
}
__device__ __forceinline__ ushort_t f2bf(float f) {
  __hip_bfloat16 b = __float2bfloat16(f);
  return *reinterpret_cast<ushort_t*>(&b);
}

// fp32 -> bf16 weight conversion (idempotent; replayed per graph launch).
__global__ void wconv(const float* __restrict__ src, ushort_t* __restrict__ dst, int n) {
  int i = blockIdx.x * blockDim.x + threadIdx.x;
  const int stride = gridDim.x * blockDim.x;
  for (; i < n; i += stride) dst[i] = f2bf(src[i]);
}

// Device-wide barrier for 256 WGs: 16 leaf counters (16 WGs each, 128B apart)
// -> root(16) -> generation bump. Agent-scope acq_rel (cross-XCD, r1-r9 proven).
__device__ __forceinline__ void gbar(unsigned long long* gs, int gw) {
  __syncthreads();
  if (threadIdx.x == 0) {
    unsigned long long* leaf = gs + (gw >> 4) * 16;
    unsigned long long* root = gs + 256;
    unsigned long long* gen  = gs + 272;
    const unsigned long long g0 = __hip_atomic_load(gen, __ATOMIC_RELAXED, __HIP_MEMORY_SCOPE_AGENT);
    const unsigned long long lo = __hip_atomic_fetch_add(leaf, 1ULL, __ATOMIC_ACQ_REL, __HIP_MEMORY_SCOPE_AGENT);
    if (lo == 15ULL) {
      __hip_atomic_store(leaf, 0ULL, __ATOMIC_RELAXED, __HIP_MEMORY_SCOPE_AGENT);
      const unsigned long long ro = __hip_atomic_fetch_add(root, 1ULL, __ATOMIC_ACQ_REL, __HIP_MEMORY_SCOPE_AGENT);
      if (ro == 15ULL) {
        __hip_atomic_store(root, 0ULL, __ATOMIC_RELAXED, __HIP_MEMORY_SCOPE_AGENT);
        __hip_atomic_fetch_add(gen, 1ULL, __ATOMIC_RELEASE, __HIP_MEMORY_SCOPE_AGENT);
      }
    }
    while (__hip_atomic_load(gen, __ATOMIC_RELAXED, __HIP_MEMORY_SCOPE_AGENT) == g0)
      __builtin_amdgcn_s_sleep(1);
    (void)__hip_atomic_load(gen, __ATOMIC_ACQUIRE, __HIP_MEMORY_SCOPE_AGENT);
  }
  __syncthreads();
}

// Bank-swizzle for slab[k][16] (r9-proven): word k*16 + (m ^ (((k>>1)&3)<<2)).
__device__ __forceinline__ int swz4(int k) { return ((k >> 1) & 3); }

// Stage slab[KS][16] (swizzled) from bf16 row-major src rows of width W.
template<int KS>
__device__ __forceinline__ void stage_bf(const ushort_t* __restrict__ src, int W,
                                         int row0, int k0, float* slab) {
  const int tid = threadIdx.x;
  const int m = tid >> 5, q = tid & 31;
  const ushort_t* sp = src + (size_t)(row0 + m) * W + k0;
  #pragma unroll
  for (int i = 0; i < KS / 32; ++i) {
    const int k = q + i * 32;
    slab[k * 16 + (m ^ (swz4(k) << 2))] = bf2f(sp[k]);
  }
}

// Fold residual + k-slice partials (4 slices of part[64][512]) + bias for
// row-block rb; optional designated write of h to hout; per-row LN stats via
// 32-lane shfl; write normalized values into slab (swizzled).
template<bool FOLD>
__device__ __forceinline__ void fold_ln(const float* __restrict__ hbase,
                                        const float* __restrict__ part,
                                        const float* __restrict__ bias,
                                        const float* __restrict__ lnw,
                                        const float* __restrict__ lnb,
                                        float* __restrict__ hout, bool writer,
                                        int rb, float* slab) {
  const int tid = threadIdx.x;
  const int m = tid >> 5, q = tid & 31;
  const size_t base = (size_t)(rb * 16 + m) * 512;
  float vv[16];
  float s = 0.f, s2 = 0.f;
  #pragma unroll
  for (int i = 0; i < 16; ++i) {
    const int k = q + i * 32;
    float v = hbase[base + k];
    if constexpr (FOLD) {
      v += part[base + k] + part[32768 + base + k]
         + part[65536 + base + k] + part[98304 + base + k] + bias[k];
      if (writer) hout[base + k] = v;
    }
    vv[i] = v; s += v; s2 += v * v;
  }
  #pragma unroll
  for (int mk = 1; mk <= 16; mk <<= 1) { s += __shfl_xor(s, mk); s2 += __shfl_xor(s2, mk); }
  const float mu = s * (1.f / 512.f);
  const float rs = rsqrtf(s2 * (1.f / 512.f) - mu * mu + 1e-5f);
  #pragma unroll
  for (int i = 0; i < 16; ++i) {
    const int k = q + i * 32;
    slab[k * 16 + (m ^ (swz4(k) << 2))] = (vv[i] - mu) * rs * lnw[k] + lnb[k];
  }
}

#define FMA_ALL(W_, A_) \
  A_[0]+=W_*a0.x; A_[1]+=W_*a0.y; A_[2]+=W_*a0.z; A_[3]+=W_*a0.w; \
  A_[4]+=W_*a1.x; A_[5]+=W_*a1.y; A_[6]+=W_*a1.z; A_[7]+=W_*a1.w; \
  A_[8]+=W_*a2.x; A_[9]+=W_*a2.y; A_[10]+=W_*a2.z; A_[11]+=W_*a2.w; \
  A_[12]+=W_*a3.x; A_[13]+=W_*a3.y; A_[14]+=W_*a3.z; A_[15]+=W_*a3.w;

// Per-WG GEMM: KS k-rows x 32 cols x 16 rows (r9-proven core).
// Returns value for (col = tid&31, m = tid>>5).
template<int KS, int N>
__device__ __forceinline__ float gemm_red(const ushort_t* __restrict__ Wbase,
                                          const float* __restrict__ slab, float* redw) {
  const int tid = threadIdx.x;
  const int wv = tid >> 6, lane = tid & 63;
  const int kq = lane >> 4, cp = lane & 15;
  constexpr int WR = KS / 8;
  constexpr int NJ = WR / 4;
  constexpr int BAT = NJ < 16 ? NJ : 16;
  const int r0 = wv * WR + kq;
  const ushort_t* Wg = Wbase + (size_t)r0 * N + cp * 2;
  float acc0[16], acc1[16];
  #pragma unroll
  for (int m = 0; m < 16; ++m) { acc0[m] = 0.f; acc1[m] = 0.f; }
  #pragma unroll
  for (int jb = 0; jb < NJ; jb += BAT) {
    unsigned w[BAT];
    #pragma unroll
    for (int u = 0; u < BAT; ++u)
      w[u] = *(const unsigned*)(Wg + (size_t)((jb + u) * 4) * N);
    #pragma unroll
    for (int u = 0; u < BAT; ++u) {
      const int row = r0 + (jb + u) * 4;
      const float4* b4 = (const float4*)(slab + row * 16);
      const int c4 = swz4(row);
      const float4 a0 = b4[0 ^ c4], a1 = b4[1 ^ c4], a2 = b4[2 ^ c4], a3 = b4[3 ^ c4];
      const float wx = bf2f((ushort_t)w[u]), wy = bf2f((ushort_t)(w[u] >> 16));
      FMA_ALL(wx, acc0)
      FMA_ALL(wy, acc1)
    }
  }
  #pragma unroll
  for (int m = 0; m < 16; ++m) {
    acc0[m] += __shfl_xor(acc0[m], 16); acc1[m] += __shfl_xor(acc1[m], 16);
    acc0[m] += __shfl_xor(acc0[m], 32); acc1[m] += __shfl_xor(acc1[m], 32);
  }
  if (lane < 16) {
    float* rp = redw + wv * 528 + lane * 33;
    #pragma unroll
    for (int m = 0; m < 16; ++m) { rp[m] = acc0[m]; rp[16 + m] = acc1[m]; }
  }
  __syncthreads();
  const int col = tid & 31, m2 = tid >> 5;
  float s = 0.f;
  #pragma unroll
  for (int w2 = 0; w2 < 8; ++w2)
    s += redw[w2 * 528 + (col >> 1) * 33 + (col & 1) * 16 + m2];
  return s;
}

__global__ __launch_bounds__(NT, 1) void gptloop(P p) {
  const int gw = blockIdx.x, tid = threadIdx.x;
  unsigned long long* sb = p.sync;

  __shared__ float slab[8192];
  __shared__ float redw[8 * 528];
  __shared__ float red1[512], red2[512];
  __shared__ float att_s[2][128];
  __shared__ float qv_s[2][64];
  __shared__ float inv_s[2];
  __shared__ float bc[4];

  // ---- init: y/u + embed(st=0) -> h0 (64 WGs, one row each) ----
  if (gw < 64) {
    const int b = gw, t = tid;
    const float y0 = p.y_d[b * 256], y1 = p.y_d[b * 256 + 1];
    const float e0 = p.r[b * 256] - y0, e1 = p.r[b * 256 + 1] - y1;
    p.h0[b * 512 + t] = e0 * p.wte_w[t] + e1 * p.wte_w[512 + t]
                      + 191.713f * p.wte_w[1024 + t] + 215.888f * p.wte_w[1536 + t]
                      + p.wte_b[t] + p.wpe[t];
    if (t < 2) {
      p.y[b * 2 + t] = t ? y1 : y0;
      p.u[b * 2 + t] = t ? 215.888f : 191.713f;
    }
  }
  gbar(sb, gw);

  for (int st = 0; st < T_; ++st) {
    for (int l = 0; l < L_; ++l) {
      // ==== A: [fold mproj(l-1) + LN1] + qkv GEMM (192 WGs = 48cb x 4rb) ====
      if (gw < 192) {
        const int cb = gw >> 2, rb = gw & 3;
        if (l == 0)
          fold_ln<false>(p.h0, nullptr, nullptr,
                         p.ln1_w + l * 512, p.ln1_b + l * 512, nullptr, false, rb, slab);
        else
          fold_ln<true>(p.h1, p.pM, p.mproj_b + (l - 1) * 512,
                        p.ln1_w + l * 512, p.ln1_b + l * 512, p.h0, cb == 0, rb, slab);
        __syncthreads();
        float v = gemm_red<512, 1536>(p.wq + (size_t)l * 786432 + cb * 32, slab, redw);
        const int col = tid & 31, m = tid >> 5;
        const int gcol = cb * 32 + col;
        v += p.qkv_b[l * 1536 + gcol];
        const int part = gcol >> 9, head = (gcol & 511) >> 6, off = gcol & 63;
        const int b = rb * 16 + m;
        if (part == 0) {
          p.qT[b * 512 + gcol] = f2bf(v * 0.125f);   // fold 1/sqrt(HD)
        } else {
          ushort_t* dst = (part == 1) ? p.Kc : p.Vc;
          dst[((size_t)(l * 64 + b) * 8 + head) * 8192 + st * 64 + off] = f2bf(v);
        }
      }
      gbar(sb, gw);

      // ==== B: attention (256 WGs x 2 (b,h) pairs) -> oT ====
      {
        const int pp = tid >> 8, t = tid & 255;
        const int pid = gw * 2 + pp, b = pid >> 3, hh = pid & 7;
        const size_t kvb = ((size_t)(l * 64 + b) * 8 + hh) * (size_t)8192;
        if (t < 64) qv_s[pp][t] = bf2f(p.qT[b * 512 + hh * 64 + t]);
        __syncthreads();
        float s = -1e30f;
        if (t <= st && t < 128) {
          const uint4* kp = (const uint4*)(p.Kc + kvb + (size_t)t * 64);
          float sc = 0.f;
          #pragma unroll
          for (int j2 = 0; j2 < 8; ++j2) {
            const uint4 k4 = kp[j2];
            sc += qv_s[pp][j2*8+0] * bf2f((ushort_t)k4.x)
                + qv_s[pp][j2*8+1] * bf2f((ushort_t)(k4.x >> 16))
                + qv_s[pp][j2*8+2] * bf2f((ushort_t)k4.y)
                + qv_s[pp][j2*8+3] * bf2f((ushort_t)(k4.y >> 16))
                + qv_s[pp][j2*8+4] * bf2f((ushort_t)k4.z)
                + qv_s[pp][j2*8+5] * bf2f((ushort_t)(k4.z >> 16))
                + qv_s[pp][j2*8+6] * bf2f((ushort_t)k4.w)
                + qv_s[pp][j2*8+7] * bf2f((ushort_t)(k4.w >> 16));
          }
          s = sc;
        }
        red1[tid] = s; __syncthreads();
        for (int s2 = 128; s2 >= 1; s2 >>= 1) {
          if (t < s2) red1[tid] = fmaxf(red1[tid], red1[tid + s2]);
          __syncthreads();
        }
        const float mx = red1[pp * 256];
        __syncthreads();
        const float e = (t <= st && t < 128) ? expf(s - mx) : 0.f;
        if (t < 128) att_s[pp][t] = e;
        red1[tid] = e; __syncthreads();
        for (int s2 = 128; s2 >= 1; s2 >>= 1) {
          if (t < s2) red1[tid] += red1[tid + s2];
          __syncthreads();
        }
        if (t == 0) inv_s[pp] = 1.f / red1[pp * 256];
        __syncthreads();
        const int d = t & 63, tq = t >> 6;
        float o = 0.f;
        for (int tt = tq; tt <= st; tt += 4)
          o += att_s[pp][tt] * bf2f(p.Vc[kvb + (size_t)tt * 64 + d]);
        red1[tid] = o; __syncthreads();
        if (tid < 128) {
          const int p2 = tid >> 6, d2 = tid & 63;
          const int pid2 = gw * 2 + p2, b2 = pid2 >> 3, h2 = pid2 & 7;
          const float oo = (red1[p2*256 + d2] + red1[p2*256 + 64 + d2]
                          + red1[p2*256 + 128 + d2] + red1[p2*256 + 192 + d2]) * inv_s[p2];
          p.oT[b2 * 512 + h2 * 64 + d2] = f2bf(oo);
        }
      }
      gbar(sb, gw);

      // ==== C: proj k-split (256 WGs = 16cb x 4ks x 4rb, K=128) -> pP ====
      {
        const int cb = gw >> 4, ks = (gw >> 2) & 3, rb = gw & 3;
        stage_bf<128>(p.oT, 512, rb * 16, ks * 128, slab);
        __syncthreads();
        const float v = gemm_red<128, 512>(
            p.wp + (size_t)l * 262144 + (size_t)(ks * 128) * 512 + cb * 32, slab, redw);
        const int col = tid & 31, m = tid >> 5;
        p.pP[(size_t)ks * 32768 + (size_t)(rb * 16 + m) * 512 + cb * 32 + col] = v;
      }
      gbar(sb, gw);

      // ==== D: [fold proj + LN2] + fc GEMM + gelu (256 WGs = 64cb x 4rb) ====
      {
        const int cb = gw >> 2, rb = gw & 3;
        fold_ln<true>(p.h0, p.pP, p.proj_b + l * 512,
                      p.ln2_w + l * 512, p.ln2_b + l * 512, p.h1, cb == 0, rb, slab);
        __syncthreads();
        float v = gemm_red<512, 2048>(p.wf + (size_t)l * 1048576 + cb * 32, slab, redw);
        const int col = tid & 31, m = tid >> 5;
        const int gcol = cb * 32 + col;
        const float x = v + p.fc_b[l * 2048 + gcol];
        p.gT[(size_t)(rb * 16 + m) * 2048 + gcol] =
            f2bf(0.5f * x * (1.f + erff(x * 0.70710678118654752f)));
      }
      gbar(sb, gw);

      // ==== E: mproj k-split (256 WGs = 16cb x 4ks x 4rb, K=512) -> pM ====
      {
        const int cb = gw >> 4, ks = (gw >> 2) & 3, rb = gw & 3;
        stage_bf<512>(p.gT, 2048, rb * 16, ks * 512, slab);
        __syncthreads();
        const float v = gemm_red<512, 512>(
            p.wm + (size_t)l * 1048576 + (size_t)(ks * 512) * 512 + cb * 32, slab, redw);
        const int col = tid & 31, m = tid >> 5;
        p.pM[(size_t)ks * 32768 + (size_t)(rb * 16 + m) * 512 + cb * 32 + col] = v;
      }
      gbar(sb, gw);
    } // layers

    // ==== F: fold mproj(7) + lnf + head + ODE + out + embed(st+1) ====
    if (gw < 64) {
      const int b = gw, t = tid;
      const size_t base = (size_t)b * 512;
      const float v = p.h1[base + t]
                    + p.pM[base + t] + p.pM[32768 + base + t]
                    + p.pM[65536 + base + t] + p.pM[98304 + base + t]
                    + p.mproj_b[7 * 512 + t];
      red1[t] = v; red2[t] = v * v;
      __syncthreads();
      for (int s2 = 256; s2 >= 1; s2 >>= 1) {
        if (t < s2) { red1[t] += red1[t + s2]; red2[t] += red2[t + s2]; }
        __syncthreads();
      }
      const float mu = red1[0] * (1.f / 512.f);
      const float rs = rsqrtf(red2[0] * (1.f / 512.f) - mu * mu + 1e-5f);
      __syncthreads();
      const float hf = (v - mu) * rs * p.lnf_w[t] + p.lnf_b[t];
      red1[t] = hf * p.head_w[t * 2];
      red2[t] = hf * p.head_w[t * 2 + 1];
      __syncthreads();
      for (int s2 = 256; s2 >= 1; s2 >>= 1) {
        if (t < s2) { red1[t] += red1[t + s2]; red2[t] += red2[t + s2]; }
        __syncthreads();
      }
      if (t < 2) {
        const float un = ((t == 0) ? red1[0] : red2[0]) + p.head_b[t];
        const float a  = p.data[b * 4 + t];
        const float bb = p.data[b * 4 + 2 + t];
        const float yv = p.y[b * 2 + t];
        p.out[b * 256 + st * 2 + t] = yv;
        const float yn = yv - a * yv + bb * un;
        p.y[b * 2 + t] = yn;
        p.u[b * 2 + t] = un;
        bc[t] = yn; bc[2 + t] = un;
      }
      __syncthreads();
      if (st < T_ - 1) {
        const float e0 = p.r[b * 256 + (st + 1) * 2]     - bc[0];
        const float e1 = p.r[b * 256 + (st + 1) * 2 + 1] - bc[1];
        p.h0[base + t] = e0 * p.wte_w[t] + e1 * p.wte_w[512 + t]
                       + bc[2] * p.wte_w[1024 + t] + bc[3] * p.wte_w[1536 + t]
                       + p.wte_b[t] + p.wpe[(st + 1) * 512 + t];
      }
    }
    gbar(sb, gw);
  } // steps
}

extern "C" void kernel_launch(void* const* d_in, const int* in_sizes, int n_in,
                              void* d_out, int out_size, void* d_ws, size_t ws_size,
                              hipStream_t stream) {
  P p;
  p.data  =(const float*)d_in[0];  p.r      =(const float*)d_in[1];
  p.y_d   =(const float*)d_in[2];  p.wte_w  =(const float*)d_in[3];
  p.wte_b =(const float*)d_in[4];  p.wpe    =(const float*)d_in[5];
  p.ln1_w =(const float*)d_in[6];  p.ln1_b  =(const float*)d_in[7];
  p.qkv_w =(const float*)d_in[8];  p.qkv_b  =(const float*)d_in[9];
  p.proj_w=(const float*)d_in[10]; p.proj_b =(const float*)d_in[11];
  p.ln2_w =(const float*)d_in[12]; p.ln2_b  =(const float*)d_in[13];
  p.fc_w  =(const float*)d_in[14]; p.fc_b   =(const float*)d_in[15];
  p.mproj_w=(const float*)d_in[16];p.mproj_b=(const float*)d_in[17];
  p.lnf_w =(const float*)d_in[18]; p.lnf_b  =(const float*)d_in[19];
  p.head_w=(const float*)d_in[20]; p.head_b =(const float*)d_in[21];
  p.out = (float*)d_out;

  char* w = (char*)d_ws;
  size_t off = 0;
  p.sync=(unsigned long long*)(w+off); off += 8192;
  p.y   =(float*)(w+off);          off += 512;
  p.u   =(float*)(w+off);          off += 512;
  p.h0  =(float*)(w+off);          off += (size_t)64*512*4;
  p.h1  =(float*)(w+off);          off += (size_t)64*512*4;
  p.pP  =(float*)(w+off);          off += (size_t)4*64*512*4;
  p.pM  =(float*)(w+off);          off += (size_t)4*64*512*4;
  p.qT  =(ushort_t*)(w+off);       off += (size_t)64*512*2;
  p.oT  =(ushort_t*)(w+off);       off += (size_t)64*512*2;
  p.gT  =(ushort_t*)(w+off);       off += (size_t)64*2048*2;
  p.wq  =(ushort_t*)(w+off);       off += (size_t)8*512*1536*2;
  p.wp  =(ushort_t*)(w+off);       off += (size_t)8*512*512*2;
  p.wf  =(ushort_t*)(w+off);       off += (size_t)8*512*2048*2;
  p.wm  =(ushort_t*)(w+off);       off += (size_t)8*2048*512*2;
  p.Kc  =(ushort_t*)(w+off);       off += (size_t)L_*64*8*T_*64*2;
  p.Vc  =(ushort_t*)(w+off);       off += (size_t)L_*64*8*T_*64*2;

  fprintf(stderr, "[gptloop] ws_size=%zu need=%zu\n", ws_size, off);
  if (ws_size < off) return;

  hipMemsetAsync(d_ws, 0, 8192, stream);
  hipLaunchKernelGGL(wconv, dim3(1024), dim3(256), 0, stream, p.qkv_w,  p.wq, 8*512*1536);
  hipLaunchKernelGGL(wconv, dim3(1024), dim3(256), 0, stream, p.proj_w, p.wp, 8*512*512);
  hipLaunchKernelGGL(wconv, dim3(1024), dim3(256), 0, stream, p.fc_w,   p.wf, 8*512*2048);
  hipLaunchKernelGGL(wconv, dim3(1024), dim3(256), 0, stream, p.mproj_w,p.wm, 8*2048*512);
  hipLaunchKernelGGL(gptloop, dim3(NWG), dim3(NT), 0, stream, p);
}

// Round 11
// 92947.357 us; speedup vs baseline: 1.5686x; 1.5686x over previous
//
#include <hip/hip_runtime.h>
#include <hip/hip_bf16.h>
#include <math.h>
#include <stdio.h>

#define NWG 256
#define NT  512
#define T_  128
#define L_  8
typedef unsigned short ushort_t;

struct P {
  const float *data,*r,*y_d,*wte_w,*wte_b,*wpe,*ln1_w,*ln1_b,*qkv_w,*qkv_b,
              *proj_w,*proj_b,*ln2_w,*ln2_b,*fc_w,*fc_b,*mproj_w,*mproj_b,
              *lnf_w,*lnf_b,*head_w,*head_b;
  float *out, *y, *u, *h0, *h1;
  ushort_t *qT, *oT, *gT;                 // bf16 activations
  ushort_t *wq, *wp, *wf, *wm;            // bf16 weights (converted at launch)
  ushort_t *Kc, *Vc;
  unsigned long long *sync;
};

__device__ __forceinline__ float bf2f(ushort_t u) {
  return __uint_as_float(((unsigned)u) << 16);
}
__device__ __forceinline__ ushort_t f2bf(float f) {
  __hip_bfloat16 b = __float2bfloat16(f);
  return *reinterpret_cast<ushort_t*>(&b);
}

// fp32 -> bf16 weight conversion (idempotent; replayed per graph launch).
__global__ void wconv(const float* __restrict__ src, ushort_t* __restrict__ dst, int n) {
  int i = blockIdx.x * blockDim.x + threadIdx.x;
  const int stride = gridDim.x * blockDim.x;
  for (; i < n; i += stride) dst[i] = f2bf(src[i]);
}

// Device-wide barrier, XCD-pure leaves: 8 leaf counters (one per XCD, 32
// arrivals each, 128B apart) -> root(8) -> generation bump. Agent-scope.
__device__ __forceinline__ void gbar(unsigned long long* gs, int xcd) {
  __syncthreads();
  if (threadIdx.x == 0) {
    unsigned long long* leaf = gs + xcd * 16;
    unsigned long long* root = gs + 128;
    unsigned long long* gen  = gs + 144;
    const unsigned long long g0 = __hip_atomic_load(gen, __ATOMIC_RELAXED, __HIP_MEMORY_SCOPE_AGENT);
    const unsigned long long lo = __hip_atomic_fetch_add(leaf, 1ULL, __ATOMIC_ACQ_REL, __HIP_MEMORY_SCOPE_AGENT);
    if (lo == 31ULL) {
      __hip_atomic_store(leaf, 0ULL, __ATOMIC_RELAXED, __HIP_MEMORY_SCOPE_AGENT);
      const unsigned long long ro = __hip_atomic_fetch_add(root, 1ULL, __ATOMIC_ACQ_REL, __HIP_MEMORY_SCOPE_AGENT);
      if (ro == 7ULL) {
        __hip_atomic_store(root, 0ULL, __ATOMIC_RELAXED, __HIP_MEMORY_SCOPE_AGENT);
        __hip_atomic_fetch_add(gen, 1ULL, __ATOMIC_RELEASE, __HIP_MEMORY_SCOPE_AGENT);
      }
    }
    while (__hip_atomic_load(gen, __ATOMIC_RELAXED, __HIP_MEMORY_SCOPE_AGENT) == g0)
      __builtin_amdgcn_s_sleep(1);
    (void)__hip_atomic_load(gen, __ATOMIC_ACQUIRE, __HIP_MEMORY_SCOPE_AGENT);
  }
  __syncthreads();
}

// Bank-swizzle for slab[k][16] (r9-proven): word k*16 + (m ^ (((k>>1)&3)<<2)).
__device__ __forceinline__ int swz4(int k) { return ((k >> 1) & 3); }

// Stage slab[512][16] (swizzled) from bf16 row-major src rows of width W.
__device__ __forceinline__ void stage_bf(const ushort_t* __restrict__ src, int W,
                                         int row0, int k0, float* slab) {
  const int tid = threadIdx.x;
  const int m = tid >> 5, q = tid & 31;
  const ushort_t* sp = src + (size_t)(row0 + m) * W + k0;
  #pragma unroll
  for (int i = 0; i < 16; ++i) {
    const int k = q + i * 32;
    slab[k * 16 + (m ^ (swz4(k) << 2))] = bf2f(sp[k]);
  }
}

// Read 16 fp32 rows of h, per-row LN stats via 32-lane shfl, write
// normalized values into slab (swizzled). Stats bitwise-match r9 path.
__device__ __forceinline__ void stats_ln(const float* __restrict__ h,
                                         const float* __restrict__ lnw,
                                         const float* __restrict__ lnb,
                                         int rb, float* slab) {
  const int tid = threadIdx.x;
  const int m = tid >> 5, q = tid & 31;
  const float* hp = h + (size_t)(rb * 16 + m) * 512;
  float vv[16];
  float s = 0.f, s2 = 0.f;
  #pragma unroll
  for (int i = 0; i < 16; ++i) {
    const int k = q + i * 32;
    const float v = hp[k];
    vv[i] = v; s += v; s2 += v * v;
  }
  #pragma unroll
  for (int mk = 1; mk <= 16; mk <<= 1) { s += __shfl_xor(s, mk); s2 += __shfl_xor(s2, mk); }
  const float mu = s * (1.f / 512.f);
  const float rs = rsqrtf(s2 * (1.f / 512.f) - mu * mu + 1e-5f);
  #pragma unroll
  for (int i = 0; i < 16; ++i) {
    const int k = q + i * 32;
    slab[k * 16 + (m ^ (swz4(k) << 2))] = (vv[i] - mu) * rs * lnw[k] + lnb[k];
  }
}

#define FMA_ALL(W_, A_) \
  A_[0]+=W_*a0.x; A_[1]+=W_*a0.y; A_[2]+=W_*a0.z; A_[3]+=W_*a0.w; \
  A_[4]+=W_*a1.x; A_[5]+=W_*a1.y; A_[6]+=W_*a1.z; A_[7]+=W_*a1.w; \
  A_[8]+=W_*a2.x; A_[9]+=W_*a2.y; A_[10]+=W_*a2.z; A_[11]+=W_*a2.w; \
  A_[12]+=W_*a3.x; A_[13]+=W_*a3.y; A_[14]+=W_*a3.z; A_[15]+=W_*a3.w;

// Accumulate one 512-k chunk: acc[2cols][16rows] += slab(512x16) @ W(512xN).
// lane = kq(lane>>4, 4-way k) x cp(lane&15, 16 col-pairs = 64B W segments);
// all 16 weight loads issued up-front. No reduction here.
template<int N>
__device__ __forceinline__ void gemm_acc(const ushort_t* __restrict__ Wbase,
                                         const float* __restrict__ slab,
                                         float* acc0, float* acc1) {
  const int tid = threadIdx.x;
  const int wv = tid >> 6, lane = tid & 63;
  const int kq = lane >> 4, cp = lane & 15;
  const int r0 = wv * 64 + kq;
  const ushort_t* Wg = Wbase + (size_t)r0 * N + cp * 2;
  unsigned w[16];
  #pragma unroll
  for (int u = 0; u < 16; ++u)
    w[u] = *(const unsigned*)(Wg + (size_t)(u * 4) * N);
  #pragma unroll
  for (int u = 0; u < 16; ++u) {
    const int row = r0 + u * 4;
    const float4* b4 = (const float4*)(slab + row * 16);
    const int c4 = swz4(row);
    const float4 a0 = b4[0 ^ c4], a1 = b4[1 ^ c4], a2 = b4[2 ^ c4], a3 = b4[3 ^ c4];
    const float wx = bf2f((ushort_t)w[u]), wy = bf2f((ushort_t)(w[u] >> 16));
    FMA_ALL(wx, acc0)
    FMA_ALL(wy, acc1)
  }
}

// Cross-lane (kq) + cross-wave reduction of acc; returns value for
// (col = tid&31, m = tid>>5).
__device__ __forceinline__ float gemm_finish(float* acc0, float* acc1, float* redw) {
  const int tid = threadIdx.x;
  const int wv = tid >> 6, lane = tid & 63;
  #pragma unroll
  for (int m = 0; m < 16; ++m) {
    acc0[m] += __shfl_xor(acc0[m], 16); acc1[m] += __shfl_xor(acc1[m], 16);
    acc0[m] += __shfl_xor(acc0[m], 32); acc1[m] += __shfl_xor(acc1[m], 32);
  }
  if (lane < 16) {
    float* rp = redw + wv * 528 + lane * 33;
    #pragma unroll
    for (int m = 0; m < 16; ++m) { rp[m] = acc0[m]; rp[16 + m] = acc1[m]; }
  }
  __syncthreads();
  const int col = tid & 31, m2 = tid >> 5;
  float s = 0.f;
  #pragma unroll
  for (int w2 = 0; w2 < 8; ++w2)
    s += redw[w2 * 528 + (col >> 1) * 33 + (col & 1) * 16 + m2];
  return s;
}

#define ACC_INIT float acc0[16], acc1[16]; \
  _Pragma("unroll") for (int m_ = 0; m_ < 16; ++m_) { acc0[m_] = 0.f; acc1[m_] = 0.f; }

__global__ __launch_bounds__(NT, 1) void gptloop(P p) {
  const int bid = blockIdx.x, tid = threadIdx.x;
  const int xcd = bid & 7, slot = bid >> 3;   // bid%8 = XCD (m09); slot 0..31
  unsigned long long* sb = p.sync;

  __shared__ float slab[8192];
  __shared__ float redw[8 * 528];
  __shared__ float red1[512], red2[512];
  __shared__ float att_s[2][128];
  __shared__ float qv_s[2][64];
  __shared__ float inv_s[2];
  __shared__ float bc[4];

  // ---- init: y/u + embed(st=0) -> h0 (64 WGs, one row each, XCD-spread) ----
  if (slot < 8) {
    const int b = xcd * 8 + slot, t = tid;
    const float y0 = p.y_d[b * 256], y1 = p.y_d[b * 256 + 1];
    const float e0 = p.r[b * 256] - y0, e1 = p.r[b * 256 + 1] - y1;
    p.h0[b * 512 + t] = e0 * p.wte_w[t] + e1 * p.wte_w[512 + t]
                      + 191.713f * p.wte_w[1024 + t] + 215.888f * p.wte_w[1536 + t]
                      + p.wte_b[t] + p.wpe[t];
    if (t < 2) {
      p.y[b * 2 + t] = t ? y1 : y0;
      p.u[b * 2 + t] = t ? 215.888f : 191.713f;
    }
  }
  gbar(sb, xcd);

  for (int st = 0; st < T_; ++st) {
    for (int l = 0; l < L_; ++l) {
      // ==== A: LN1-stats + qkv full-K (192 WGs: xcd owns 6 cb x 4 rb) ====
      if (slot < 24) {
        const int cb = xcd * 6 + (slot >> 2), rb = slot & 3;
        stats_ln(p.h0, p.ln1_w + l * 512, p.ln1_b + l * 512, rb, slab);
        __syncthreads();
        ACC_INIT
        gemm_acc<1536>(p.wq + (size_t)l * 786432 + cb * 32, slab, acc0, acc1);
        float v = gemm_finish(acc0, acc1, redw);
        const int col = tid & 31, m = tid >> 5;
        const int gcol = cb * 32 + col;
        v += p.qkv_b[l * 1536 + gcol];
        const int part = gcol >> 9, head = (gcol & 511) >> 6, off = gcol & 63;
        const int b = rb * 16 + m;
        if (part == 0) {
          p.qT[b * 512 + gcol] = f2bf(v * 0.125f);   // fold 1/sqrt(HD)
        } else {
          ushort_t* dst = (part == 1) ? p.Kc : p.Vc;
          dst[((size_t)(l * 64 + b) * 8 + head) * 8192 + st * 64 + off] = f2bf(v);
        }
      }
      gbar(sb, xcd);

      // ==== B: attention (256 WGs x 2 (b,h) pairs) -> oT ====
      {
        const int pp = tid >> 8, t = tid & 255;
        const int pid = bid * 2 + pp, b = pid >> 3, hh = pid & 7;
        const size_t kvb = ((size_t)(l * 64 + b) * 8 + hh) * (size_t)8192;
        if (t < 64) qv_s[pp][t] = bf2f(p.qT[b * 512 + hh * 64 + t]);
        __syncthreads();
        float s = -1e30f;
        if (t <= st && t < 128) {
          const uint4* kp = (const uint4*)(p.Kc + kvb + (size_t)t * 64);
          float sc = 0.f;
          #pragma unroll
          for (int j2 = 0; j2 < 8; ++j2) {
            const uint4 k4 = kp[j2];
            sc += qv_s[pp][j2*8+0] * bf2f((ushort_t)k4.x)
                + qv_s[pp][j2*8+1] * bf2f((ushort_t)(k4.x >> 16))
                + qv_s[pp][j2*8+2] * bf2f((ushort_t)k4.y)
                + qv_s[pp][j2*8+3] * bf2f((ushort_t)(k4.y >> 16))
                + qv_s[pp][j2*8+4] * bf2f((ushort_t)k4.z)
                + qv_s[pp][j2*8+5] * bf2f((ushort_t)(k4.z >> 16))
                + qv_s[pp][j2*8+6] * bf2f((ushort_t)k4.w)
                + qv_s[pp][j2*8+7] * bf2f((ushort_t)(k4.w >> 16));
          }
          s = sc;
        }
        red1[tid] = s; __syncthreads();
        for (int s2 = 128; s2 >= 1; s2 >>= 1) {
          if (t < s2) red1[tid] = fmaxf(red1[tid], red1[tid + s2]);
          __syncthreads();
        }
        const float mx = red1[pp * 256];
        __syncthreads();
        const float e = (t <= st && t < 128) ? expf(s - mx) : 0.f;
        if (t < 128) att_s[pp][t] = e;
        red1[tid] = e; __syncthreads();
        for (int s2 = 128; s2 >= 1; s2 >>= 1) {
          if (t < s2) red1[tid] += red1[tid + s2];
          __syncthreads();
        }
        if (t == 0) inv_s[pp] = 1.f / red1[pp * 256];
        __syncthreads();
        const int d = t & 63, tq = t >> 6;
        float o = 0.f;
        for (int tt = tq; tt <= st; tt += 4)
          o += att_s[pp][tt] * bf2f(p.Vc[kvb + (size_t)tt * 64 + d]);
        red1[tid] = o; __syncthreads();
        if (tid < 128) {
          const int p2 = tid >> 6, d2 = tid & 63;
          const int pid2 = bid * 2 + p2, b2 = pid2 >> 3, h2 = pid2 & 7;
          const float oo = (red1[p2*256 + d2] + red1[p2*256 + 64 + d2]
                          + red1[p2*256 + 128 + d2] + red1[p2*256 + 192 + d2]) * inv_s[p2];
          p.oT[b2 * 512 + h2 * 64 + d2] = f2bf(oo);
        }
      }
      gbar(sb, xcd);

      // ==== C: proj full-K + residual -> h1 (64 WGs: xcd owns 2 cb x 4 rb) ====
      if (slot < 8) {
        const int cb = xcd * 2 + (slot >> 2), rb = slot & 3;
        stage_bf(p.oT, 512, rb * 16, 0, slab);
        __syncthreads();
        ACC_INIT
        gemm_acc<512>(p.wp + (size_t)l * 262144 + cb * 32, slab, acc0, acc1);
        const float v = gemm_finish(acc0, acc1, redw);
        const int col = tid & 31, m = tid >> 5;
        const int gcol = cb * 32 + col, row = rb * 16 + m;
        p.h1[row * 512 + gcol] = p.h0[row * 512 + gcol] + v + p.proj_b[l * 512 + gcol];
      }
      gbar(sb, xcd);

      // ==== D: LN2-stats + fc full-K + gelu -> gT (256 WGs: 8 cb x 4 rb per xcd) ====
      {
        const int cb = xcd * 8 + (slot >> 2), rb = slot & 3;
        stats_ln(p.h1, p.ln2_w + l * 512, p.ln2_b + l * 512, rb, slab);
        __syncthreads();
        ACC_INIT
        gemm_acc<2048>(p.wf + (size_t)l * 1048576 + cb * 32, slab, acc0, acc1);
        const float v = gemm_finish(acc0, acc1, redw);
        const int col = tid & 31, m = tid >> 5;
        const int gcol = cb * 32 + col;
        const float x = v + p.fc_b[l * 2048 + gcol];
        p.gT[(size_t)(rb * 16 + m) * 2048 + gcol] =
            f2bf(0.5f * x * (1.f + erff(x * 0.70710678118654752f)));
      }
      gbar(sb, xcd);

      // ==== E: mproj full-K (4 seq 512-chunks) + residual -> h0 (64 WGs) ====
      if (slot < 8) {
        const int cb = xcd * 2 + (slot >> 2), rb = slot & 3;
        ACC_INIT
        for (int ch = 0; ch < 4; ++ch) {
          __syncthreads();
          stage_bf(p.gT, 2048, rb * 16, ch * 512, slab);
          __syncthreads();
          gemm_acc<512>(p.wm + (size_t)l * 1048576 + (size_t)(ch * 512) * 512 + cb * 32,
                        slab, acc0, acc1);
        }
        const float v = gemm_finish(acc0, acc1, redw);
        const int col = tid & 31, m = tid >> 5;
        const int gcol = cb * 32 + col, row = rb * 16 + m;
        p.h0[row * 512 + gcol] = p.h1[row * 512 + gcol] + v + p.mproj_b[l * 512 + gcol];
      }
      gbar(sb, xcd);
    } // layers

    // ==== F: lnf + head + ODE + out + embed(st+1) (64 WGs, one row each) ====
    if (slot < 8) {
      const int b = xcd * 8 + slot, t = tid;
      const float v = p.h0[b * 512 + t];
      red1[t] = v; red2[t] = v * v;
      __syncthreads();
      for (int s2 = 256; s2 >= 1; s2 >>= 1) {
        if (t < s2) { red1[t] += red1[t + s2]; red2[t] += red2[t + s2]; }
        __syncthreads();
      }
      const float mu = red1[0] * (1.f / 512.f);
      const float rs = rsqrtf(red2[0] * (1.f / 512.f) - mu * mu + 1e-5f);
      __syncthreads();
      const float hf = (v - mu) * rs * p.lnf_w[t] + p.lnf_b[t];
      red1[t] = hf * p.head_w[t * 2];
      red2[t] = hf * p.head_w[t * 2 + 1];
      __syncthreads();
      for (int s2 = 256; s2 >= 1; s2 >>= 1) {
        if (t < s2) { red1[t] += red1[t + s2]; red2[t] += red2[t + s2]; }
        __syncthreads();
      }
      if (t < 2) {
        const float un = ((t == 0) ? red1[0] : red2[0]) + p.head_b[t];
        const float a  = p.data[b * 4 + t];
        const float bb = p.data[b * 4 + 2 + t];
        const float yv = p.y[b * 2 + t];
        p.out[b * 256 + st * 2 + t] = yv;
        const float yn = yv - a * yv + bb * un;
        p.y[b * 2 + t] = yn;
        p.u[b * 2 + t] = un;
        bc[t] = yn; bc[2 + t] = un;
      }
      __syncthreads();
      if (st < T_ - 1) {
        const float e0 = p.r[b * 256 + (st + 1) * 2]     - bc[0];
        const float e1 = p.r[b * 256 + (st + 1) * 2 + 1] - bc[1];
        p.h0[b * 512 + t] = e0 * p.wte_w[t] + e1 * p.wte_w[512 + t]
                          + bc[2] * p.wte_w[1024 + t] + bc[3] * p.wte_w[1536 + t]
                          + p.wte_b[t] + p.wpe[(st + 1) * 512 + t];
      }
    }
    gbar(sb, xcd);
  } // steps
}

extern "C" void kernel_launch(void* const* d_in, const int* in_sizes, int n_in,
                              void* d_out, int out_size, void* d_ws, size_t ws_size,
                              hipStream_t stream) {
  P p;
  p.data  =(const float*)d_in[0];  p.r      =(const float*)d_in[1];
  p.y_d   =(const float*)d_in[2];  p.wte_w  =(const float*)d_in[3];
  p.wte_b =(const float*)d_in[4];  p.wpe    =(const float*)d_in[5];
  p.ln1_w =(const float*)d_in[6];  p.ln1_b  =(const float*)d_in[7];
  p.qkv_w =(const float*)d_in[8];  p.qkv_b  =(const float*)d_in[9];
  p.proj_w=(const float*)d_in[10]; p.proj_b =(const float*)d_in[11];
  p.ln2_w =(const float*)d_in[12]; p.ln2_b  =(const float*)d_in[13];
  p.fc_w  =(const float*)d_in[14]; p.fc_b   =(const float*)d_in[15];
  p.mproj_w=(const float*)d_in[16];p.mproj_b=(const float*)d_in[17];
  p.lnf_w =(const float*)d_in[18]; p.lnf_b  =(const float*)d_in[19];
  p.head_w=(const float*)d_in[20]; p.head_b =(const float*)d_in[21];
  p.out = (float*)d_out;

  char* w = (char*)d_ws;
  size_t off = 0;
  p.sync=(unsigned long long*)(w+off); off += 8192;
  p.y   =(float*)(w+off);          off += 512;
  p.u   =(float*)(w+off);          off += 512;
  p.h0  =(float*)(w+off);          off += (size_t)64*512*4;
  p.h1  =(float*)(w+off);          off += (size_t)64*512*4;
  p.qT  =(ushort_t*)(w+off);       off += (size_t)64*512*2;
  p.oT  =(ushort_t*)(w+off);       off += (size_t)64*512*2;
  p.gT  =(ushort_t*)(w+off);       off += (size_t)64*2048*2;
  p.wq  =(ushort_t*)(w+off);       off += (size_t)8*512*1536*2;
  p.wp  =(ushort_t*)(w+off);       off += (size_t)8*512*512*2;
  p.wf  =(ushort_t*)(w+off);       off += (size_t)8*512*2048*2;
  p.wm  =(ushort_t*)(w+off);       off += (size_t)8*2048*512*2;
  p.Kc  =(ushort_t*)(w+off);       off += (size_t)L_*64*8*T_*64*2;
  p.Vc  =(ushort_t*)(w+off);       off += (size_t)L_*64*8*T_*64*2;

  fprintf(stderr, "[gptloop] ws_size=%zu need=%zu\n", ws_size, off);
  if (ws_size < off) return;

  hipMemsetAsync(d_ws, 0, 8192, stream);
  hipLaunchKernelGGL(wconv, dim3(1024), dim3(256), 0, stream, p.qkv_w,  p.wq, 8*512*1536);
  hipLaunchKernelGGL(wconv, dim3(1024), dim3(256), 0, stream, p.proj_w, p.wp, 8*512*512);
  hipLaunchKernelGGL(wconv, dim3(1024), dim3(256), 0, stream, p.fc_w,   p.wf, 8*512*2048);
  hipLaunchKernelGGL(wconv, dim3(1024), dim3(256), 0, stream, p.mproj_w,p.wm, 8*2048*512);
  hipLaunchKernelGGL(gptloop, dim3(NWG), dim3(NT), 0, stream, p);
}

// Round 12
// 66994.739 us; speedup vs baseline: 2.1762x; 1.3874x over previous
//
#include <hip/hip_runtime.h>
#include <hip/hip_bf16.h>
#include <math.h>
#include <stdio.h>

#define NWG 256
#define NT  512
#define T_  128
#define L_  8
typedef unsigned short ushort_t;

struct P {
  const float *data,*r,*y_d,*wte_w,*wte_b,*wpe,*ln1_w,*ln1_b,*qkv_w,*qkv_b,
              *proj_w,*proj_b,*ln2_w,*ln2_b,*fc_w,*fc_b,*mproj_w,*mproj_b,
              *lnf_w,*lnf_b,*head_w,*head_b;
  float *out, *y, *u, *h0, *h1;
  ushort_t *qT, *oT, *gT;                 // bf16 activations
  ushort_t *wq, *wp, *wf, *wm;            // bf16 weights (converted at launch)
  ushort_t *Kc, *Vc;
  unsigned long long *sync;
};

__device__ __forceinline__ float bf2f(ushort_t u) {
  return __uint_as_float(((unsigned)u) << 16);
}
__device__ __forceinline__ ushort_t f2bf(float f) {
  __hip_bfloat16 b = __float2bfloat16(f);
  return *reinterpret_cast<ushort_t*>(&b);
}

// fp32 -> bf16 weight conversion (idempotent; replayed per graph launch).
__global__ void wconv(const float* __restrict__ src, ushort_t* __restrict__ dst, int n) {
  int i = blockIdx.x * blockDim.x + threadIdx.x;
  const int stride = gridDim.x * blockDim.x;
  for (; i < n; i += stride) dst[i] = f2bf(src[i]);
}

// Barrier v3 — minimal cache-op multiplicity.
// Leaf arrivals are RELAXED (no L2 writeback/invalidate per WG). Correctness:
// each WG's __syncthreads() (vmcnt(0)) has landed its stores in its XCD's L2
// BEFORE its leaf RMW; the last arriver per XCD therefore flushes all 32 WGs'
// data with ONE RELEASE (wbl2) on the root RMW. Gen bump = RELEASE; waiters
// poll RELAXED and do ONE ACQUIRE (inv) on wake.
// Per barrier: 8 wbl2 + 256 inv (was 256 wbl2 + ~512 inv with acq_rel arrivals).
__device__ __forceinline__ void gbar(unsigned long long* gs, int xcd) {
  __syncthreads();
  if (threadIdx.x == 0) {
    unsigned long long* leaf = gs + xcd * 16;
    unsigned long long* root = gs + 128;
    unsigned long long* gen  = gs + 144;
    const unsigned long long g0 = __hip_atomic_load(gen, __ATOMIC_RELAXED, __HIP_MEMORY_SCOPE_AGENT);
    const unsigned long long lo = __hip_atomic_fetch_add(leaf, 1ULL, __ATOMIC_RELAXED, __HIP_MEMORY_SCOPE_AGENT);
    if (lo == 31ULL) {
      __hip_atomic_store(leaf, 0ULL, __ATOMIC_RELAXED, __HIP_MEMORY_SCOPE_AGENT);
      const unsigned long long ro = __hip_atomic_fetch_add(root, 1ULL, __ATOMIC_RELEASE, __HIP_MEMORY_SCOPE_AGENT);
      if (ro == 7ULL) {
        __hip_atomic_store(root, 0ULL, __ATOMIC_RELAXED, __HIP_MEMORY_SCOPE_AGENT);
        __hip_atomic_fetch_add(gen, 1ULL, __ATOMIC_RELEASE, __HIP_MEMORY_SCOPE_AGENT);
      }
    }
    while (__hip_atomic_load(gen, __ATOMIC_RELAXED, __HIP_MEMORY_SCOPE_AGENT) == g0)
      __builtin_amdgcn_s_sleep(2);
    (void)__hip_atomic_load(gen, __ATOMIC_ACQUIRE, __HIP_MEMORY_SCOPE_AGENT);
  }
  __syncthreads();
}

// Bank-swizzle for slab[k][16] (r9-proven): word k*16 + (m ^ (((k>>1)&3)<<2)).
__device__ __forceinline__ int swz4(int k) { return ((k >> 1) & 3); }

// Stage slab[512][16] (swizzled) from bf16 row-major src rows of width W.
__device__ __forceinline__ void stage_bf(const ushort_t* __restrict__ src, int W,
                                         int row0, int k0, float* slab) {
  const int tid = threadIdx.x;
  const int m = tid >> 5, q = tid & 31;
  const ushort_t* sp = src + (size_t)(row0 + m) * W + k0;
  #pragma unroll
  for (int i = 0; i < 16; ++i) {
    const int k = q + i * 32;
    slab[k * 16 + (m ^ (swz4(k) << 2))] = bf2f(sp[k]);
  }
}

// Read 16 fp32 rows of h, per-row LN stats via 32-lane shfl, write
// normalized values into slab (swizzled).
__device__ __forceinline__ void stats_ln(const float* __restrict__ h,
                                         const float* __restrict__ lnw,
                                         const float* __restrict__ lnb,
                                         int rb, float* slab) {
  const int tid = threadIdx.x;
  const int m = tid >> 5, q = tid & 31;
  const float* hp = h + (size_t)(rb * 16 + m) * 512;
  float vv[16];
  float s = 0.f, s2 = 0.f;
  #pragma unroll
  for (int i = 0; i < 16; ++i) {
    const int k = q + i * 32;
    const float v = hp[k];
    vv[i] = v; s += v; s2 += v * v;
  }
  #pragma unroll
  for (int mk = 1; mk <= 16; mk <<= 1) { s += __shfl_xor(s, mk); s2 += __shfl_xor(s2, mk); }
  const float mu = s * (1.f / 512.f);
  const float rs = rsqrtf(s2 * (1.f / 512.f) - mu * mu + 1e-5f);
  #pragma unroll
  for (int i = 0; i < 16; ++i) {
    const int k = q + i * 32;
    slab[k * 16 + (m ^ (swz4(k) << 2))] = (vv[i] - mu) * rs * lnw[k] + lnb[k];
  }
}

#define FMA_ALL(W_, A_) \
  A_[0]+=W_*a0.x; A_[1]+=W_*a0.y; A_[2]+=W_*a0.z; A_[3]+=W_*a0.w; \
  A_[4]+=W_*a1.x; A_[5]+=W_*a1.y; A_[6]+=W_*a1.z; A_[7]+=W_*a1.w; \
  A_[8]+=W_*a2.x; A_[9]+=W_*a2.y; A_[10]+=W_*a2.z; A_[11]+=W_*a2.w; \
  A_[12]+=W_*a3.x; A_[13]+=W_*a3.y; A_[14]+=W_*a3.z; A_[15]+=W_*a3.w;

// Accumulate one 512-k chunk: acc[2cols][16rows] += slab(512x16) @ W(512xN).
template<int N>
__device__ __forceinline__ void gemm_acc(const ushort_t* __restrict__ Wbase,
                                         const float* __restrict__ slab,
                                         float* acc0, float* acc1) {
  const int tid = threadIdx.x;
  const int wv = tid >> 6, lane = tid & 63;
  const int kq = lane >> 4, cp = lane & 15;
  const int r0 = wv * 64 + kq;
  const ushort_t* Wg = Wbase + (size_t)r0 * N + cp * 2;
  unsigned w[16];
  #pragma unroll
  for (int u = 0; u < 16; ++u)
    w[u] = *(const unsigned*)(Wg + (size_t)(u * 4) * N);
  #pragma unroll
  for (int u = 0; u < 16; ++u) {
    const int row = r0 + u * 4;
    const float4* b4 = (const float4*)(slab + row * 16);
    const int c4 = swz4(row);
    const float4 a0 = b4[0 ^ c4], a1 = b4[1 ^ c4], a2 = b4[2 ^ c4], a3 = b4[3 ^ c4];
    const float wx = bf2f((ushort_t)w[u]), wy = bf2f((ushort_t)(w[u] >> 16));
    FMA_ALL(wx, acc0)
    FMA_ALL(wy, acc1)
  }
}

// Cross-lane (kq) + cross-wave reduction of acc; returns value for
// (col = tid&31, m = tid>>5).
__device__ __forceinline__ float gemm_finish(float* acc0, float* acc1, float* redw) {
  const int tid = threadIdx.x;
  const int wv = tid >> 6, lane = tid & 63;
  #pragma unroll
  for (int m = 0; m < 16; ++m) {
    acc0[m] += __shfl_xor(acc0[m], 16); acc1[m] += __shfl_xor(acc1[m], 16);
    acc0[m] += __shfl_xor(acc0[m], 32); acc1[m] += __shfl_xor(acc1[m], 32);
  }
  if (lane < 16) {
    float* rp = redw + wv * 528 + lane * 33;
    #pragma unroll
    for (int m = 0; m < 16; ++m) { rp[m] = acc0[m]; rp[16 + m] = acc1[m]; }
  }
  __syncthreads();
  const int col = tid & 31, m2 = tid >> 5;
  float s = 0.f;
  #pragma unroll
  for (int w2 = 0; w2 < 8; ++w2)
    s += redw[w2 * 528 + (col >> 1) * 33 + (col & 1) * 16 + m2];
  return s;
}

#define ACC_INIT float acc0[16], acc1[16]; \
  _Pragma("unroll") for (int m_ = 0; m_ < 16; ++m_) { acc0[m_] = 0.f; acc1[m_] = 0.f; }

__global__ __launch_bounds__(NT, 1) void gptloop(P p) {
  const int bid = blockIdx.x, tid = threadIdx.x;
  const int xcd = bid & 7, slot = bid >> 3;   // bid%8 = XCD (m09); slot 0..31
  unsigned long long* sb = p.sync;

  __shared__ float slab[8192];
  __shared__ float redw[8 * 528];
  __shared__ float red1[512], red2[512];
  __shared__ float att_s[2][128];
  __shared__ float qv_s[2][64];
  __shared__ float inv_s[2];
  __shared__ float bc[4];

  // ---- init: y/u + embed(st=0) -> h0 (64 WGs, one row each, XCD-spread) ----
  if (slot < 8) {
    const int b = xcd * 8 + slot, t = tid;
    const float y0 = p.y_d[b * 256], y1 = p.y_d[b * 256 + 1];
    const float e0 = p.r[b * 256] - y0, e1 = p.r[b * 256 + 1] - y1;
    p.h0[b * 512 + t] = e0 * p.wte_w[t] + e1 * p.wte_w[512 + t]
                      + 191.713f * p.wte_w[1024 + t] + 215.888f * p.wte_w[1536 + t]
                      + p.wte_b[t] + p.wpe[t];
    if (t < 2) {
      p.y[b * 2 + t] = t ? y1 : y0;
      p.u[b * 2 + t] = t ? 215.888f : 191.713f;
    }
  }
  gbar(sb, xcd);

  for (int st = 0; st < T_; ++st) {
    for (int l = 0; l < L_; ++l) {
      // ==== A: LN1-stats + qkv full-K (192 WGs: xcd owns 6 cb x 4 rb) ====
      if (slot < 24) {
        const int cb = xcd * 6 + (slot >> 2), rb = slot & 3;
        stats_ln(p.h0, p.ln1_w + l * 512, p.ln1_b + l * 512, rb, slab);
        __syncthreads();
        ACC_INIT
        gemm_acc<1536>(p.wq + (size_t)l * 786432 + cb * 32, slab, acc0, acc1);
        float v = gemm_finish(acc0, acc1, redw);
        const int col = tid & 31, m = tid >> 5;
        const int gcol = cb * 32 + col;
        v += p.qkv_b[l * 1536 + gcol];
        const int part = gcol >> 9, head = (gcol & 511) >> 6, off = gcol & 63;
        const int b = rb * 16 + m;
        if (part == 0) {
          p.qT[b * 512 + gcol] = f2bf(v * 0.125f);   // fold 1/sqrt(HD)
        } else {
          ushort_t* dst = (part == 1) ? p.Kc : p.Vc;
          dst[((size_t)(l * 64 + b) * 8 + head) * 8192 + st * 64 + off] = f2bf(v);
        }
      }
      gbar(sb, xcd);

      // ==== B: attention (256 WGs x 2 (b,h) pairs) -> oT ====
      {
        const int pp = tid >> 8, t = tid & 255;
        const int pid = bid * 2 + pp, b = pid >> 3, hh = pid & 7;
        const size_t kvb = ((size_t)(l * 64 + b) * 8 + hh) * (size_t)8192;
        if (t < 64) qv_s[pp][t] = bf2f(p.qT[b * 512 + hh * 64 + t]);
        __syncthreads();
        float s = -1e30f;
        if (t <= st && t < 128) {
          const uint4* kp = (const uint4*)(p.Kc + kvb + (size_t)t * 64);
          float sc = 0.f;
          #pragma unroll
          for (int j2 = 0; j2 < 8; ++j2) {
            const uint4 k4 = kp[j2];
            sc += qv_s[pp][j2*8+0] * bf2f((ushort_t)k4.x)
                + qv_s[pp][j2*8+1] * bf2f((ushort_t)(k4.x >> 16))
                + qv_s[pp][j2*8+2] * bf2f((ushort_t)k4.y)
                + qv_s[pp][j2*8+3] * bf2f((ushort_t)(k4.y >> 16))
                + qv_s[pp][j2*8+4] * bf2f((ushort_t)k4.z)
                + qv_s[pp][j2*8+5] * bf2f((ushort_t)(k4.z >> 16))
                + qv_s[pp][j2*8+6] * bf2f((ushort_t)k4.w)
                + qv_s[pp][j2*8+7] * bf2f((ushort_t)(k4.w >> 16));
          }
          s = sc;
        }
        red1[tid] = s; __syncthreads();
        for (int s2 = 128; s2 >= 1; s2 >>= 1) {
          if (t < s2) red1[tid] = fmaxf(red1[tid], red1[tid + s2]);
          __syncthreads();
        }
        const float mx = red1[pp * 256];
        __syncthreads();
        const float e = (t <= st && t < 128) ? expf(s - mx) : 0.f;
        if (t < 128) att_s[pp][t] = e;
        red1[tid] = e; __syncthreads();
        for (int s2 = 128; s2 >= 1; s2 >>= 1) {
          if (t < s2) red1[tid] += red1[tid + s2];
          __syncthreads();
        }
        if (t == 0) inv_s[pp] = 1.f / red1[pp * 256];
        __syncthreads();
        const int d = t & 63, tq = t >> 6;
        float o = 0.f;
        for (int tt = tq; tt <= st; tt += 4)
          o += att_s[pp][tt] * bf2f(p.Vc[kvb + (size_t)tt * 64 + d]);
        red1[tid] = o; __syncthreads();
        if (tid < 128) {
          const int p2 = tid >> 6, d2 = tid & 63;
          const int pid2 = bid * 2 + p2, b2 = pid2 >> 3, h2 = pid2 & 7;
          const float oo = (red1[p2*256 + d2] + red1[p2*256 + 64 + d2]
                          + red1[p2*256 + 128 + d2] + red1[p2*256 + 192 + d2]) * inv_s[p2];
          p.oT[b2 * 512 + h2 * 64 + d2] = f2bf(oo);
        }
      }
      gbar(sb, xcd);

      // ==== C: proj full-K + residual -> h1 (64 WGs: xcd owns 2 cb x 4 rb) ====
      if (slot < 8) {
        const int cb = xcd * 2 + (slot >> 2), rb = slot & 3;
        stage_bf(p.oT, 512, rb * 16, 0, slab);
        __syncthreads();
        ACC_INIT
        gemm_acc<512>(p.wp + (size_t)l * 262144 + cb * 32, slab, acc0, acc1);
        const float v = gemm_finish(acc0, acc1, redw);
        const int col = tid & 31, m = tid >> 5;
        const int gcol = cb * 32 + col, row = rb * 16 + m;
        p.h1[row * 512 + gcol] = p.h0[row * 512 + gcol] + v + p.proj_b[l * 512 + gcol];
      }
      gbar(sb, xcd);

      // ==== D: LN2-stats + fc full-K + gelu -> gT (256 WGs: 8 cb x 4 rb per xcd) ====
      {
        const int cb = xcd * 8 + (slot >> 2), rb = slot & 3;
        stats_ln(p.h1, p.ln2_w + l * 512, p.ln2_b + l * 512, rb, slab);
        __syncthreads();
        ACC_INIT
        gemm_acc<2048>(p.wf + (size_t)l * 1048576 + cb * 32, slab, acc0, acc1);
        const float v = gemm_finish(acc0, acc1, redw);
        const int col = tid & 31, m = tid >> 5;
        const int gcol = cb * 32 + col;
        const float x = v + p.fc_b[l * 2048 + gcol];
        p.gT[(size_t)(rb * 16 + m) * 2048 + gcol] =
            f2bf(0.5f * x * (1.f + erff(x * 0.70710678118654752f)));
      }
      gbar(sb, xcd);

      // ==== E: mproj full-K (4 seq 512-chunks) + residual -> h0 (64 WGs) ====
      if (slot < 8) {
        const int cb = xcd * 2 + (slot >> 2), rb = slot & 3;
        ACC_INIT
        for (int ch = 0; ch < 4; ++ch) {
          __syncthreads();
          stage_bf(p.gT, 2048, rb * 16, ch * 512, slab);
          __syncthreads();
          gemm_acc<512>(p.wm + (size_t)l * 1048576 + (size_t)(ch * 512) * 512 + cb * 32,
                        slab, acc0, acc1);
        }
        const float v = gemm_finish(acc0, acc1, redw);
        const int col = tid & 31, m = tid >> 5;
        const int gcol = cb * 32 + col, row = rb * 16 + m;
        p.h0[row * 512 + gcol] = p.h1[row * 512 + gcol] + v + p.mproj_b[l * 512 + gcol];
      }
      gbar(sb, xcd);
    } // layers

    // ==== F: lnf + head + ODE + out + embed(st+1) (64 WGs, one row each) ====
    if (slot < 8) {
      const int b = xcd * 8 + slot, t = tid;
      const float v = p.h0[b * 512 + t];
      red1[t] = v; red2[t] = v * v;
      __syncthreads();
      for (int s2 = 256; s2 >= 1; s2 >>= 1) {
        if (t < s2) { red1[t] += red1[t + s2]; red2[t] += red2[t + s2]; }
        __syncthreads();
      }
      const float mu = red1[0] * (1.f / 512.f);
      const float rs = rsqrtf(red2[0] * (1.f / 512.f) - mu * mu + 1e-5f);
      __syncthreads();
      const float hf = (v - mu) * rs * p.lnf_w[t] + p.lnf_b[t];
      red1[t] = hf * p.head_w[t * 2];
      red2[t] = hf * p.head_w[t * 2 + 1];
      __syncthreads();
      for (int s2 = 256; s2 >= 1; s2 >>= 1) {
        if (t < s2) { red1[t] += red1[t + s2]; red2[t] += red2[t + s2]; }
        __syncthreads();
      }
      if (t < 2) {
        const float un = ((t == 0) ? red1[0] : red2[0]) + p.head_b[t];
        const float a  = p.data[b * 4 + t];
        const float bb = p.data[b * 4 + 2 + t];
        const float yv = p.y[b * 2 + t];
        p.out[b * 256 + st * 2 + t] = yv;
        const float yn = yv - a * yv + bb * un;
        p.y[b * 2 + t] = yn;
        p.u[b * 2 + t] = un;
        bc[t] = yn; bc[2 + t] = un;
      }
      __syncthreads();
      if (st < T_ - 1) {
        const float e0 = p.r[b * 256 + (st + 1) * 2]     - bc[0];
        const float e1 = p.r[b * 256 + (st + 1) * 2 + 1] - bc[1];
        p.h0[b * 512 + t] = e0 * p.wte_w[t] + e1 * p.wte_w[512 + t]
                          + bc[2] * p.wte_w[1024 + t] + bc[3] * p.wte_w[1536 + t]
                          + p.wte_b[t] + p.wpe[(st + 1) * 512 + t];
      }
    }
    gbar(sb, xcd);
  } // steps
}

extern "C" void kernel_launch(void* const* d_in, const int* in_sizes, int n_in,
                              void* d_out, int out_size, void* d_ws, size_t ws_size,
                              hipStream_t stream) {
  P p;
  p.data  =(const float*)d_in[0];  p.r      =(const float*)d_in[1];
  p.y_d   =(const float*)d_in[2];  p.wte_w  =(const float*)d_in[3];
  p.wte_b =(const float*)d_in[4];  p.wpe    =(const float*)d_in[5];
  p.ln1_w =(const float*)d_in[6];  p.ln1_b  =(const float*)d_in[7];
  p.qkv_w =(const float*)d_in[8];  p.qkv_b  =(const float*)d_in[9];
  p.proj_w=(const float*)d_in[10]; p.proj_b =(const float*)d_in[11];
  p.ln2_w =(const float*)d_in[12]; p.ln2_b =(const float*)d_in[13];
  p.fc_w  =(const float*)d_in[14]; p.fc_b   =(const float*)d_in[15];
  p.mproj_w=(const float*)d_in[16];p.mproj_b=(const float*)d_in[17];
  p.lnf_w =(const float*)d_in[18]; p.lnf_b  =(const float*)d_in[19];
  p.head_w=(const float*)d_in[20]; p.head_b =(const float*)d_in[21];
  p.out = (float*)d_out;

  char* w = (char*)d_ws;
  size_t off = 0;
  p.sync=(unsigned long long*)(w+off); off += 8192;
  p.y   =(float*)(w+off);          off += 512;
  p.u   =(float*)(w+off);          off += 512;
  p.h0  =(float*)(w+off);          off += (size_t)64*512*4;
  p.h1  =(float*)(w+off);          off += (size_t)64*512*4;
  p.qT  =(ushort_t*)(w+off);       off += (size_t)64*512*2;
  p.oT  =(ushort_t*)(w+off);       off += (size_t)64*512*2;
  p.gT  =(ushort_t*)(w+off);       off += (size_t)64*2048*2;
  p.wq  =(ushort_t*)(w+off);       off += (size_t)8*512*1536*2;
  p.wp  =(ushort_t*)(w+off);       off += (size_t)8*512*512*2;
  p.wf  =(ushort_t*)(w+off);       off += (size_t)8*512*2048*2;
  p.wm  =(ushort_t*)(w+off);       off += (size_t)8*2048*512*2;
  p.Kc  =(ushort_t*)(w+off);       off += (size_t)L_*64*8*T_*64*2;
  p.Vc  =(ushort_t*)(w+off);       off += (size_t)L_*64*8*T_*64*2;

  fprintf(stderr, "[gptloop] ws_size=%zu need=%zu\n", ws_size, off);
  if (ws_size < off) return;

  hipMemsetAsync(d_ws, 0, 8192, stream);
  hipLaunchKernelGGL(wconv, dim3(1024), dim3(256), 0, stream, p.qkv_w,  p.wq, 8*512*1536);
  hipLaunchKernelGGL(wconv, dim3(1024), dim3(256), 0, stream, p.proj_w, p.wp, 8*512*512);
  hipLaunchKernelGGL(wconv, dim3(1024), dim3(256), 0, stream, p.fc_w,   p.wf, 8*512*2048);
  hipLaunchKernelGGL(wconv, dim3(1024), dim3(256), 0, stream, p.mproj_w,p.wm, 8*2048*512);
  hipLaunchKernelGGL(gptloop, dim3(NWG), dim3(NT), 0, stream, p);
}